// Round 2
// baseline (757.528 us; speedup 1.0000x reference)
//
#include <hip/hip_runtime.h>
#include <hip/hip_fp16.h>

// Trilinear grid-sample, sorted-gather pipeline:
//  1. transform: feats [B,F,D,H,W] f32 -> T [B,D,H,W,F] fp16 (channels-last,
//     x-pair of 8 feats = 32B contiguous; 128 MiB, L3-resident).
//  2. counting sort of the 2^20 samples by 8x8x8-voxel spatial bin
//     (zero-hist, atomic histogram, 1-block prefix scan, scatter payload
//     {x,y,z,idx} + inverse permutation).
//  3. gather pass in SORTED order: a wave's 64 lanes sample the same
//     ~12 KB tile region -> gather lines are shared across lanes and
//     L2-resident (fixes the divergent-gather TA serialization that
//     bounded the unsorted version). Writes sorted results coalesced.
//  4. unpermute: invperm-indexed coalesced rewrite into [B,F,Hg,Wg].

#define NB 4
#define NF 8
#define ND 128
#define NH 128
#define NW 128
#define HG 512
#define WG 512

#define PTOT (HG * WG)            // 262144 samples per batch
#define TOTAL (NB * PTOT)         // 1048576 samples
#define NBINS (NB * 16 * 16 * 16) // 16384 bins (8^3-voxel tiles)

typedef float        __attribute__((ext_vector_type(4))) f32x4;
typedef unsigned int __attribute__((ext_vector_type(4))) u32x4;

// ---------------- pass 1: layout transform ----------------
__global__ __launch_bounds__(256) void transform_kernel(
    const float* __restrict__ feats, __half* __restrict__ T)
{
    const size_t S = (size_t)ND * NH * NW;
    size_t tid = (size_t)blockIdx.x * blockDim.x + threadIdx.x;
    size_t b  = tid / (S / 4);
    size_t s4 = (tid - b * (S / 4)) * 4;

    const float* fb = feats + b * NF * S;
    __half* tb = T + (b * S + s4) * NF;

    f32x4 vals[NF];
#pragma unroll
    for (int f = 0; f < NF; ++f)
        vals[f] = __builtin_nontemporal_load(
            (const f32x4*)(fb + (size_t)f * S + s4));

#pragma unroll
    for (int i = 0; i < 4; ++i) {
        u32x4 hv;
#pragma unroll
        for (int f = 0; f < 4; ++f) {
            __half2 h = __floats2half2_rn(vals[2 * f][i], vals[2 * f + 1][i]);
            hv[f] = *(const unsigned*)&h;
        }
        *(u32x4*)(tb + (size_t)i * NF) = hv;   // cached: want T in L3
    }
}

// ---------------- shared coordinate helper ----------------
__device__ __forceinline__ void grid_to_voxel(
    const float* __restrict__ g, float& x, float& y, float& z)
{
    x = __builtin_nontemporal_load(g + 0);
    y = __builtin_nontemporal_load(g + 1);
    z = __builtin_nontemporal_load(g + 2);
    x = fminf(fmaxf(x, -1.0f), 1.0f);
    y = fminf(fmaxf(y, -1.0f), 1.0f);
    z = fminf(fmaxf(z, -1.0f), 1.0f);
    x = (x + 1.0f) * 0.5f * (float)(NW - 1);
    y = (y + 1.0f) * 0.5f * (float)(NH - 1);
    z = (z + 1.0f) * 0.5f * (float)(ND - 1);
}

__device__ __forceinline__ int sample_bin(int idx, float x, float y, float z)
{
    int ix0 = min(max((int)floorf(x), 0), NW - 1);
    int iy0 = min(max((int)floorf(y), 0), NH - 1);
    int iz0 = min(max((int)floorf(z), 0), ND - 1);
    return ((((idx >> 18) * 16 + (iz0 >> 3)) * 16 + (iy0 >> 3)) * 16) + (ix0 >> 3);
}

// ---------------- sort passes ----------------
__global__ __launch_bounds__(256) void zero_kernel(unsigned* __restrict__ hist)
{
    hist[blockIdx.x * blockDim.x + threadIdx.x] = 0u;   // 64 blocks x 256 = 16384
}

__global__ __launch_bounds__(256) void hist_kernel(
    const float* __restrict__ grid, unsigned* __restrict__ hist)
{
    int idx = blockIdx.x * blockDim.x + threadIdx.x;
    float x, y, z;
    grid_to_voxel(grid + (size_t)idx * 3, x, y, z);
    atomicAdd(&hist[sample_bin(idx, x, y, z)], 1u);
}

__global__ __launch_bounds__(1024) void scan_kernel(unsigned* __restrict__ hist)
{
    __shared__ unsigned part[1024];
    int t = threadIdx.x;
    unsigned v[16];
    unsigned s = 0;
#pragma unroll
    for (int i = 0; i < 16; ++i) { v[i] = hist[t * 16 + i]; s += v[i]; }
    part[t] = s;
    __syncthreads();
    for (int off = 1; off < 1024; off <<= 1) {
        unsigned add = (t >= off) ? part[t - off] : 0u;
        __syncthreads();
        part[t] += add;
        __syncthreads();
    }
    unsigned ex = (t == 0) ? 0u : part[t - 1];
#pragma unroll
    for (int i = 0; i < 16; ++i) { hist[t * 16 + i] = ex; ex += v[i]; }
}

__global__ __launch_bounds__(256) void scatter_kernel(
    const float* __restrict__ grid, unsigned* __restrict__ cursor,
    u32x4* __restrict__ payload, unsigned* __restrict__ invperm)
{
    int idx = blockIdx.x * blockDim.x + threadIdx.x;
    float x, y, z;
    grid_to_voxel(grid + (size_t)idx * 3, x, y, z);
    int bin = sample_bin(idx, x, y, z);
    unsigned slot = atomicAdd(&cursor[bin], 1u);
    u32x4 pl;
    pl.x = __float_as_uint(x);
    pl.y = __float_as_uint(y);
    pl.z = __float_as_uint(z);
    pl.w = (unsigned)idx;
    payload[slot] = pl;
    invperm[idx] = slot;
}

// ---------------- sorted gather ----------------
__device__ __forceinline__ void pair_accum(
    const u32x4& lov, const u32x4& hiv, bool hi,
    float wr, float um, float u, float acc[NF])
{
    u32x4 c0 = hi ? hiv : lov;                // x-edge clamp (ix0==127)
    const u32x4& c1 = hiv;
#pragma unroll
    for (int j = 0; j < 4; ++j) {
        unsigned u0 = c0[j], u1 = c1[j];
        float2 f0 = __half22float2(*(const __half2*)&u0);
        float2 f1 = __half22float2(*(const __half2*)&u1);
        acc[2 * j]     = fmaf(wr, fmaf(u, f1.x, um * f0.x), acc[2 * j]);
        acc[2 * j + 1] = fmaf(wr, fmaf(u, f1.y, um * f0.y), acc[2 * j + 1]);
    }
}

__global__ __launch_bounds__(256) void gather_kernel(
    const __half* __restrict__ T, const u32x4* __restrict__ payload,
    float* __restrict__ outT)
{
    int slot = blockIdx.x * blockDim.x + threadIdx.x;
    u32x4 pl = payload[slot];
    float x = __uint_as_float(pl.x);
    float y = __uint_as_float(pl.y);
    float z = __uint_as_float(pl.z);
    int b = (int)(pl.w >> 18);

    float xf = floorf(x), yf = floorf(y), zf = floorf(z);
    float u = x - xf, v = y - yf, w = z - zf;
    float um = 1.0f - u, vm = 1.0f - v, wm = 1.0f - w;

    int ix0 = min(max((int)xf, 0), NW - 1);
    int iy0 = min(max((int)yf, 0), NH - 1);
    int iy1 = min(iy0 + 1, NH - 1);
    int iz0 = min(max((int)zf, 0), ND - 1);
    int iz1 = min(iz0 + 1, ND - 1);

    int xb = min(ix0, NW - 2);
    bool hi = (ix0 != xb);

    const __half* tb = T + (size_t)b * ((size_t)ND * NH * NW) * NF;
    size_t r00 = ((size_t)(iz0 * NH + iy0) * NW + xb) * NF;
    size_t r01 = ((size_t)(iz0 * NH + iy1) * NW + xb) * NF;
    size_t r10 = ((size_t)(iz1 * NH + iy0) * NW + xb) * NF;
    size_t r11 = ((size_t)(iz1 * NH + iy1) * NW + xb) * NF;

    u32x4 L[8];
    L[0] = *(const u32x4*)(tb + r00);
    L[1] = *(const u32x4*)(tb + r00 + NF);
    L[2] = *(const u32x4*)(tb + r01);
    L[3] = *(const u32x4*)(tb + r01 + NF);
    L[4] = *(const u32x4*)(tb + r10);
    L[5] = *(const u32x4*)(tb + r10 + NF);
    L[6] = *(const u32x4*)(tb + r11);
    L[7] = *(const u32x4*)(tb + r11 + NF);

    float acc[NF];
#pragma unroll
    for (int f = 0; f < NF; ++f) acc[f] = 0.0f;

    pair_accum(L[0], L[1], hi, wm * vm, um, u, acc);
    pair_accum(L[2], L[3], hi, wm * v,  um, u, acc);
    pair_accum(L[4], L[5], hi, w  * vm, um, u, acc);
    pair_accum(L[6], L[7], hi, w  * v,  um, u, acc);

    f32x4* op = (f32x4*)(outT + (size_t)slot * NF);
    f32x4 o0, o1;
#pragma unroll
    for (int j = 0; j < 4; ++j) { o0[j] = acc[j]; o1[j] = acc[4 + j]; }
    op[0] = o0;     // coalesced 32B/lane, sorted order
    op[1] = o1;
}

// ---------------- unpermute ----------------
__global__ __launch_bounds__(256) void unperm_kernel(
    const float* __restrict__ outT, const unsigned* __restrict__ invperm,
    float* __restrict__ out)
{
    int i = blockIdx.x * blockDim.x + threadIdx.x;
    unsigned slot = invperm[i];               // coalesced read
    const f32x4* ip = (const f32x4*)(outT + (size_t)slot * NF);
    f32x4 a = ip[0];                          // random 32B read, L2/L3-resident
    f32x4 c = ip[1];
    int b = i >> 18;
    int p = i & (PTOT - 1);
    float* o = out + (size_t)b * NF * PTOT + p;
#pragma unroll
    for (int j = 0; j < 4; ++j) {
        __builtin_nontemporal_store(a[j], o + (size_t)j * PTOT);
        __builtin_nontemporal_store(c[j], o + (size_t)(4 + j) * PTOT);
    }
}

// ---------------- fallbacks ----------------
__global__ __launch_bounds__(256) void trilerp_half_kernel(
    const __half* __restrict__ T,
    const float* __restrict__ grid,
    float* __restrict__ out)
{
    const int P = HG * WG;
    int idx = blockIdx.x * blockDim.x + threadIdx.x;
    int b = idx >> 18;
    int p = idx & (P - 1);

    float x, y, z;
    grid_to_voxel(grid + (size_t)idx * 3, x, y, z);

    float xf = floorf(x), yf = floorf(y), zf = floorf(z);
    float u = x - xf, v = y - yf, w = z - zf;
    float um = 1.0f - u, vm = 1.0f - v, wm = 1.0f - w;

    int ix0 = min(max((int)xf, 0), NW - 1);
    int iy0 = min(max((int)yf, 0), NH - 1);
    int iy1 = min(iy0 + 1, NH - 1);
    int iz0 = min(max((int)zf, 0), ND - 1);
    int iz1 = min(iz0 + 1, ND - 1);

    int xb = min(ix0, NW - 2);
    bool hi = (ix0 != xb);

    const __half* tb = T + (size_t)b * ((size_t)ND * NH * NW) * NF;
    size_t r00 = ((size_t)(iz0 * NH + iy0) * NW + xb) * NF;
    size_t r01 = ((size_t)(iz0 * NH + iy1) * NW + xb) * NF;
    size_t r10 = ((size_t)(iz1 * NH + iy0) * NW + xb) * NF;
    size_t r11 = ((size_t)(iz1 * NH + iy1) * NW + xb) * NF;

    u32x4 L[8];
    L[0] = *(const u32x4*)(tb + r00);
    L[1] = *(const u32x4*)(tb + r00 + NF);
    L[2] = *(const u32x4*)(tb + r01);
    L[3] = *(const u32x4*)(tb + r01 + NF);
    L[4] = *(const u32x4*)(tb + r10);
    L[5] = *(const u32x4*)(tb + r10 + NF);
    L[6] = *(const u32x4*)(tb + r11);
    L[7] = *(const u32x4*)(tb + r11 + NF);

    float acc[NF];
#pragma unroll
    for (int f = 0; f < NF; ++f) acc[f] = 0.0f;

    pair_accum(L[0], L[1], hi, wm * vm, um, u, acc);
    pair_accum(L[2], L[3], hi, wm * v,  um, u, acc);
    pair_accum(L[4], L[5], hi, w  * vm, um, u, acc);
    pair_accum(L[6], L[7], hi, w  * v,  um, u, acc);

    float* o = out + (size_t)b * NF * P + p;
#pragma unroll
    for (int f = 0; f < NF; ++f)
        __builtin_nontemporal_store(acc[f], o + (size_t)f * P);
}

__global__ __launch_bounds__(256) void trilerp_f32_kernel(
    const float* __restrict__ feats,
    const float* __restrict__ grid,
    float* __restrict__ out)
{
    const int P = HG * WG;
    int idx = blockIdx.x * blockDim.x + threadIdx.x;
    int b = idx >> 18;
    int p = idx & (P - 1);

    const float* g = grid + (size_t)idx * 3;
    float x = g[0], y = g[1], z = g[2];
    x = fminf(fmaxf(x, -1.0f), 1.0f);
    y = fminf(fmaxf(y, -1.0f), 1.0f);
    z = fminf(fmaxf(z, -1.0f), 1.0f);
    x = (x + 1.0f) * 0.5f * (float)(NW - 1);
    y = (y + 1.0f) * 0.5f * (float)(NH - 1);
    z = (z + 1.0f) * 0.5f * (float)(ND - 1);

    float xf = floorf(x), yf = floorf(y), zf = floorf(z);
    float u = x - xf, v = y - yf, w = z - zf;

    int ix0 = min(max((int)xf, 0), NW - 1);
    int ix1 = min(ix0 + 1, NW - 1);
    int iy0 = min(max((int)yf, 0), NH - 1);
    int iy1 = min(iy0 + 1, NH - 1);
    int iz0 = min(max((int)zf, 0), ND - 1);
    int iz1 = min(iz0 + 1, ND - 1);

    float um = 1.0f - u, vm = 1.0f - v, wm = 1.0f - w;
    float w000 = um * vm * wm, w100 = u * vm * wm;
    float w010 = um * v * wm,  w110 = u * v * wm;
    float w001 = um * vm * w,  w101 = u * vm * w;
    float w011 = um * v * w,   w111 = u * v * w;

    int off00 = (iz0 * NH + iy0) * NW;
    int off01 = (iz0 * NH + iy1) * NW;
    int off10 = (iz1 * NH + iy0) * NW;
    int off11 = (iz1 * NH + iy1) * NW;

    const size_t fstride = (size_t)ND * NH * NW;
    const float* fb = feats + (size_t)b * NF * fstride;
    float* o = out + (size_t)b * NF * P + p;

#pragma unroll
    for (int f = 0; f < NF; ++f) {
        const float* fp = fb + (size_t)f * fstride;
        float r = w000 * fp[off00 + ix0] + w100 * fp[off00 + ix1]
                + w010 * fp[off01 + ix0] + w110 * fp[off01 + ix1]
                + w001 * fp[off10 + ix0] + w101 * fp[off10 + ix1]
                + w011 * fp[off11 + ix0] + w111 * fp[off11 + ix1];
        o[(size_t)f * P] = r;
    }
}

extern "C" void kernel_launch(void* const* d_in, const int* in_sizes, int n_in,
                              void* d_out, int out_size, void* d_ws, size_t ws_size,
                              hipStream_t stream) {
    const float* feats = (const float*)d_in[0];
    const float* grid  = (const float*)d_in[1];
    float* out = (float*)d_out;

    const size_t T_BYTES    = (size_t)NB * ND * NH * NW * NF * sizeof(__half); // 128 MiB
    const size_t OFF_PAYL   = T_BYTES;                                          // +16 MiB
    const size_t OFF_OUTT   = OFF_PAYL + (size_t)TOTAL * 16;                    // +32 MiB
    const size_t OFF_INVP   = OFF_OUTT + (size_t)TOTAL * NF * sizeof(float);    // +4 MiB
    const size_t OFF_HIST   = OFF_INVP + (size_t)TOTAL * sizeof(unsigned);      // +64 KiB
    const size_t NEED_FULL  = OFF_HIST + (size_t)NBINS * sizeof(unsigned);      // ~181 MiB

    if (ws_size >= NEED_FULL) {
        char* ws = (char*)d_ws;
        __half*   T       = (__half*)ws;
        u32x4*    payload = (u32x4*)(ws + OFF_PAYL);
        float*    outT    = (float*)(ws + OFF_OUTT);
        unsigned* invperm = (unsigned*)(ws + OFF_INVP);
        unsigned* hist    = (unsigned*)(ws + OFF_HIST);

        const int tthreads = NB * ND * NH * NW / 4;              // 2^21
        transform_kernel<<<tthreads / 256, 256, 0, stream>>>(feats, T);

        zero_kernel<<<NBINS / 256, 256, 0, stream>>>(hist);
        hist_kernel<<<TOTAL / 256, 256, 0, stream>>>(grid, hist);
        scan_kernel<<<1, 1024, 0, stream>>>(hist);
        scatter_kernel<<<TOTAL / 256, 256, 0, stream>>>(grid, hist, payload, invperm);
        gather_kernel<<<TOTAL / 256, 256, 0, stream>>>(T, payload, outT);
        unperm_kernel<<<TOTAL / 256, 256, 0, stream>>>(outT, invperm, out);
    } else if (ws_size >= T_BYTES) {
        __half* T = (__half*)d_ws;
        const int tthreads = NB * ND * NH * NW / 4;
        transform_kernel<<<tthreads / 256, 256, 0, stream>>>(feats, T);
        const int total = NB * HG * WG;
        trilerp_half_kernel<<<total / 256, 256, 0, stream>>>(T, grid, out);
    } else {
        const int total = NB * HG * WG;
        trilerp_f32_kernel<<<total / 256, 256, 0, stream>>>(feats, grid, out);
    }
}

// Round 3
// 483.848 us; speedup vs baseline: 1.5656x; 1.5656x over previous
//
#include <hip/hip_runtime.h>
#include <hip/hip_fp16.h>

// Trilinear grid-sample, cheap-sorted-gather pipeline:
//  1. transform: feats [B,F,D,H,W] f32 -> T [B,D,H,W,F] fp16 (channels-last;
//     x-pair of 8 feats = 32B contiguous; 128 MiB, L3-resident).
//  2. counting sort of samples by COARSE bin = (batch, z>>2): 128 bins,
//     1 MiB z-slab per bin (fits one XCD L2). Atomic-free 3-pass partition:
//       a) per-block LDS hist -> counts[bin][blk]   (no global atomics)
//       b) single-block scan -> absolute base offsets per (bin, blk)
//       c) scatter via LDS cursors -> payload[slot]={x,y,z,idx}
//  3. gather in sorted order, XCD-range-partitioned (chunk swizzle) so each
//     z-slab is pulled into exactly one XCD's L2 once. Writes 32B result to
//     outT[original idx] (random, L2-absorbed) - no inverse permutation.
//  4. finalize: fully-coalesced outT -> out[B,F,Hg,Wg] NT rewrite.

#define NB 4
#define NF 8
#define ND 128
#define NH 128
#define NW 128
#define HG 512
#define WG 512

#define PTOT (HG * WG)            // 262144 samples per batch
#define TOTAL (NB * PTOT)         // 1048576 samples
#define NBINS_C (NB * 32)         // 128 coarse bins: (batch, z>>2)
#define HBLK 512                  // hist/scatter blocks
#define SPB (TOTAL / HBLK)        // 2048 samples per hist/scatter block

typedef float        __attribute__((ext_vector_type(4))) f32x4;
typedef unsigned int __attribute__((ext_vector_type(4))) u32x4;

// ---------------- pass 1: layout transform ----------------
__global__ __launch_bounds__(256) void transform_kernel(
    const float* __restrict__ feats, __half* __restrict__ T)
{
    const size_t S = (size_t)ND * NH * NW;
    size_t tid = (size_t)blockIdx.x * blockDim.x + threadIdx.x;
    size_t b  = tid / (S / 4);
    size_t s4 = (tid - b * (S / 4)) * 4;

    const float* fb = feats + b * NF * S;
    __half* tb = T + (b * S + s4) * NF;

    f32x4 vals[NF];
#pragma unroll
    for (int f = 0; f < NF; ++f)
        vals[f] = __builtin_nontemporal_load(
            (const f32x4*)(fb + (size_t)f * S + s4));

#pragma unroll
    for (int i = 0; i < 4; ++i) {
        u32x4 hv;
#pragma unroll
        for (int f = 0; f < 4; ++f) {
            __half2 h = __floats2half2_rn(vals[2 * f][i], vals[2 * f + 1][i]);
            hv[f] = *(const unsigned*)&h;
        }
        *(u32x4*)(tb + (size_t)i * NF) = hv;   // cached: want T in L3
    }
}

// ---------------- helpers ----------------
__device__ __forceinline__ void grid_to_voxel(
    const float* __restrict__ g, float& x, float& y, float& z)
{
    x = __builtin_nontemporal_load(g + 0);
    y = __builtin_nontemporal_load(g + 1);
    z = __builtin_nontemporal_load(g + 2);
    x = fminf(fmaxf(x, -1.0f), 1.0f);
    y = fminf(fmaxf(y, -1.0f), 1.0f);
    z = fminf(fmaxf(z, -1.0f), 1.0f);
    x = (x + 1.0f) * 0.5f * (float)(NW - 1);
    y = (y + 1.0f) * 0.5f * (float)(NH - 1);
    z = (z + 1.0f) * 0.5f * (float)(ND - 1);
}

__device__ __forceinline__ int sample_bin(int idx, float z)
{
    int iz0 = min(max((int)floorf(z), 0), ND - 1);
    return ((idx >> 18) << 5) | (iz0 >> 2);       // (batch, z-slab)
}

// ---------------- sort pass a: per-block histogram (LDS only) ----------------
__global__ __launch_bounds__(256) void hist_kernel(
    const float* __restrict__ grid, unsigned* __restrict__ counts)
{
    __shared__ unsigned h[NBINS_C];
    int t = threadIdx.x, blk = blockIdx.x;
    if (t < NBINS_C) h[t] = 0u;
    __syncthreads();
#pragma unroll
    for (int k = 0; k < SPB / 256; ++k) {
        int idx = blk * SPB + k * 256 + t;
        float x, y, z;
        grid_to_voxel(grid + (size_t)idx * 3, x, y, z);
        atomicAdd(&h[sample_bin(idx, z)], 1u);
    }
    __syncthreads();
    if (t < NBINS_C) counts[(size_t)t * HBLK + blk] = h[t];
}

// ---------------- sort pass b: scan (one block) ----------------
__global__ __launch_bounds__(128) void scan_kernel(unsigned* __restrict__ counts)
{
    __shared__ unsigned tot[NBINS_C];
    int t = threadIdx.x;                      // one thread per bin
    unsigned s = 0;
    for (int k = 0; k < HBLK; ++k) s += counts[(size_t)t * HBLK + k];
    tot[t] = s;
    __syncthreads();
    for (int off = 1; off < NBINS_C; off <<= 1) {
        unsigned add = (t >= off) ? tot[t - off] : 0u;
        __syncthreads();
        tot[t] += add;
        __syncthreads();
    }
    unsigned run = (t == 0) ? 0u : tot[t - 1];   // exclusive bin base
    for (int k = 0; k < HBLK; ++k) {
        unsigned c = counts[(size_t)t * HBLK + k];
        counts[(size_t)t * HBLK + k] = run;
        run += c;
    }
}

// ---------------- sort pass c: scatter (LDS cursors, no global atomics) ----
__global__ __launch_bounds__(256) void scatter_kernel(
    const float* __restrict__ grid, const unsigned* __restrict__ counts,
    u32x4* __restrict__ payload)
{
    __shared__ unsigned cur[NBINS_C];
    int t = threadIdx.x, blk = blockIdx.x;
    if (t < NBINS_C) cur[t] = counts[(size_t)t * HBLK + blk];
    __syncthreads();
#pragma unroll
    for (int k = 0; k < SPB / 256; ++k) {
        int idx = blk * SPB + k * 256 + t;
        float x, y, z;
        grid_to_voxel(grid + (size_t)idx * 3, x, y, z);
        int bin = sample_bin(idx, z);
        unsigned slot = atomicAdd(&cur[bin], 1u);
        u32x4 pl;
        pl.x = __float_as_uint(x);
        pl.y = __float_as_uint(y);
        pl.z = __float_as_uint(z);
        pl.w = (unsigned)idx;
        payload[slot] = pl;
    }
}

// ---------------- gather (sorted order, XCD-partitioned) ----------------
__device__ __forceinline__ void pair_accum(
    const u32x4& lov, const u32x4& hiv, bool hi,
    float wr, float um, float u, float acc[NF])
{
    u32x4 c0 = hi ? hiv : lov;                // x-edge clamp (ix0==127)
    const u32x4& c1 = hiv;
#pragma unroll
    for (int j = 0; j < 4; ++j) {
        unsigned u0 = c0[j], u1 = c1[j];
        float2 f0 = __half22float2(*(const __half2*)&u0);
        float2 f1 = __half22float2(*(const __half2*)&u1);
        acc[2 * j]     = fmaf(wr, fmaf(u, f1.x, um * f0.x), acc[2 * j]);
        acc[2 * j + 1] = fmaf(wr, fmaf(u, f1.y, um * f0.y), acc[2 * j + 1]);
    }
}

__global__ __launch_bounds__(256) void gather_kernel(
    const __half* __restrict__ T, const u32x4* __restrict__ payload,
    float* __restrict__ outT)
{
    // XCD range partition: blocks dispatch round-robin to the 8 XCDs, so
    // XCD x walks contiguous sorted chunks [x*512, (x+1)*512) -> each z-slab
    // enters exactly one XCD's L2.
    int bid = blockIdx.x;                          // 0..4095
    int chunk = (bid & 7) * ((TOTAL / 256) / 8) + (bid >> 3);
    int slot = chunk * 256 + threadIdx.x;

    u32x4 pl = payload[slot];
    float x = __uint_as_float(pl.x);
    float y = __uint_as_float(pl.y);
    float z = __uint_as_float(pl.z);
    int b = (int)(pl.w >> 18);

    float xf = floorf(x), yf = floorf(y), zf = floorf(z);
    float u = x - xf, v = y - yf, w = z - zf;
    float um = 1.0f - u, vm = 1.0f - v, wm = 1.0f - w;

    int ix0 = min(max((int)xf, 0), NW - 1);
    int iy0 = min(max((int)yf, 0), NH - 1);
    int iy1 = min(iy0 + 1, NH - 1);
    int iz0 = min(max((int)zf, 0), ND - 1);
    int iz1 = min(iz0 + 1, ND - 1);

    int xb = min(ix0, NW - 2);
    bool hi = (ix0 != xb);

    const __half* tb = T + (size_t)b * ((size_t)ND * NH * NW) * NF;
    size_t r00 = ((size_t)(iz0 * NH + iy0) * NW + xb) * NF;
    size_t r01 = ((size_t)(iz0 * NH + iy1) * NW + xb) * NF;
    size_t r10 = ((size_t)(iz1 * NH + iy0) * NW + xb) * NF;
    size_t r11 = ((size_t)(iz1 * NH + iy1) * NW + xb) * NF;

    u32x4 L[8];
    L[0] = *(const u32x4*)(tb + r00);
    L[1] = *(const u32x4*)(tb + r00 + NF);
    L[2] = *(const u32x4*)(tb + r01);
    L[3] = *(const u32x4*)(tb + r01 + NF);
    L[4] = *(const u32x4*)(tb + r10);
    L[5] = *(const u32x4*)(tb + r10 + NF);
    L[6] = *(const u32x4*)(tb + r11);
    L[7] = *(const u32x4*)(tb + r11 + NF);

    float acc[NF];
#pragma unroll
    for (int f = 0; f < NF; ++f) acc[f] = 0.0f;

    pair_accum(L[0], L[1], hi, wm * vm, um, u, acc);
    pair_accum(L[2], L[3], hi, wm * v,  um, u, acc);
    pair_accum(L[4], L[5], hi, w  * vm, um, u, acc);
    pair_accum(L[6], L[7], hi, w  * v,  um, u, acc);

    // Write to ORIGINAL index -> finalize pass is fully coalesced.
    float* op = outT + (size_t)pl.w * NF;
    f32x4 o0, o1;
#pragma unroll
    for (int j = 0; j < 4; ++j) { o0[j] = acc[j]; o1[j] = acc[4 + j]; }
    *(f32x4*)op       = o0;
    *(f32x4*)(op + 4) = o1;
}

// ---------------- finalize: coalesced rewrite ----------------
__global__ __launch_bounds__(256) void finalize_kernel(
    const float* __restrict__ outT, float* __restrict__ out)
{
    int i = blockIdx.x * blockDim.x + threadIdx.x;
    const f32x4* ip = (const f32x4*)(outT + (size_t)i * NF);  // coalesced
    f32x4 a = ip[0];
    f32x4 c = ip[1];
    int b = i >> 18;
    int p = i & (PTOT - 1);
    float* o = out + (size_t)b * NF * PTOT + p;
#pragma unroll
    for (int j = 0; j < 4; ++j) {
        __builtin_nontemporal_store(a[j], o + (size_t)j * PTOT);
        __builtin_nontemporal_store(c[j], o + (size_t)(4 + j) * PTOT);
    }
}

// ---------------- fallbacks ----------------
__global__ __launch_bounds__(256) void trilerp_half_kernel(
    const __half* __restrict__ T,
    const float* __restrict__ grid,
    float* __restrict__ out)
{
    const int P = HG * WG;
    int idx = blockIdx.x * blockDim.x + threadIdx.x;
    int b = idx >> 18;
    int p = idx & (P - 1);

    float x, y, z;
    grid_to_voxel(grid + (size_t)idx * 3, x, y, z);

    float xf = floorf(x), yf = floorf(y), zf = floorf(z);
    float u = x - xf, v = y - yf, w = z - zf;
    float um = 1.0f - u, vm = 1.0f - v, wm = 1.0f - w;

    int ix0 = min(max((int)xf, 0), NW - 1);
    int iy0 = min(max((int)yf, 0), NH - 1);
    int iy1 = min(iy0 + 1, NH - 1);
    int iz0 = min(max((int)zf, 0), ND - 1);
    int iz1 = min(iz0 + 1, ND - 1);

    int xb = min(ix0, NW - 2);
    bool hi = (ix0 != xb);

    const __half* tb = T + (size_t)b * ((size_t)ND * NH * NW) * NF;
    size_t r00 = ((size_t)(iz0 * NH + iy0) * NW + xb) * NF;
    size_t r01 = ((size_t)(iz0 * NH + iy1) * NW + xb) * NF;
    size_t r10 = ((size_t)(iz1 * NH + iy0) * NW + xb) * NF;
    size_t r11 = ((size_t)(iz1 * NH + iy1) * NW + xb) * NF;

    u32x4 L[8];
    L[0] = *(const u32x4*)(tb + r00);
    L[1] = *(const u32x4*)(tb + r00 + NF);
    L[2] = *(const u32x4*)(tb + r01);
    L[3] = *(const u32x4*)(tb + r01 + NF);
    L[4] = *(const u32x4*)(tb + r10);
    L[5] = *(const u32x4*)(tb + r10 + NF);
    L[6] = *(const u32x4*)(tb + r11);
    L[7] = *(const u32x4*)(tb + r11 + NF);

    float acc[NF];
#pragma unroll
    for (int f = 0; f < NF; ++f) acc[f] = 0.0f;

    pair_accum(L[0], L[1], hi, wm * vm, um, u, acc);
    pair_accum(L[2], L[3], hi, wm * v,  um, u, acc);
    pair_accum(L[4], L[5], hi, w  * vm, um, u, acc);
    pair_accum(L[6], L[7], hi, w  * v,  um, u, acc);

    float* o = out + (size_t)b * NF * P + p;
#pragma unroll
    for (int f = 0; f < NF; ++f)
        __builtin_nontemporal_store(acc[f], o + (size_t)f * P);
}

__global__ __launch_bounds__(256) void trilerp_f32_kernel(
    const float* __restrict__ feats,
    const float* __restrict__ grid,
    float* __restrict__ out)
{
    const int P = HG * WG;
    int idx = blockIdx.x * blockDim.x + threadIdx.x;
    int b = idx >> 18;
    int p = idx & (P - 1);

    const float* g = grid + (size_t)idx * 3;
    float x = g[0], y = g[1], z = g[2];
    x = fminf(fmaxf(x, -1.0f), 1.0f);
    y = fminf(fmaxf(y, -1.0f), 1.0f);
    z = fminf(fmaxf(z, -1.0f), 1.0f);
    x = (x + 1.0f) * 0.5f * (float)(NW - 1);
    y = (y + 1.0f) * 0.5f * (float)(NH - 1);
    z = (z + 1.0f) * 0.5f * (float)(ND - 1);

    float xf = floorf(x), yf = floorf(y), zf = floorf(z);
    float u = x - xf, v = y - yf, w = z - zf;

    int ix0 = min(max((int)xf, 0), NW - 1);
    int ix1 = min(ix0 + 1, NW - 1);
    int iy0 = min(max((int)yf, 0), NH - 1);
    int iy1 = min(iy0 + 1, NH - 1);
    int iz0 = min(max((int)zf, 0), ND - 1);
    int iz1 = min(iz0 + 1, ND - 1);

    float um = 1.0f - u, vm = 1.0f - v, wm = 1.0f - w;
    float w000 = um * vm * wm, w100 = u * vm * wm;
    float w010 = um * v * wm,  w110 = u * v * wm;
    float w001 = um * vm * w,  w101 = u * vm * w;
    float w011 = um * v * w,   w111 = u * v * w;

    int off00 = (iz0 * NH + iy0) * NW;
    int off01 = (iz0 * NH + iy1) * NW;
    int off10 = (iz1 * NH + iy0) * NW;
    int off11 = (iz1 * NH + iy1) * NW;

    const size_t fstride = (size_t)ND * NH * NW;
    const float* fb = feats + (size_t)b * NF * fstride;
    float* o = out + (size_t)b * NF * P + p;

#pragma unroll
    for (int f = 0; f < NF; ++f) {
        const float* fp = fb + (size_t)f * fstride;
        float r = w000 * fp[off00 + ix0] + w100 * fp[off00 + ix1]
                + w010 * fp[off01 + ix0] + w110 * fp[off01 + ix1]
                + w001 * fp[off10 + ix0] + w101 * fp[off10 + ix1]
                + w011 * fp[off11 + ix0] + w111 * fp[off11 + ix1];
        o[(size_t)f * P] = r;
    }
}

extern "C" void kernel_launch(void* const* d_in, const int* in_sizes, int n_in,
                              void* d_out, int out_size, void* d_ws, size_t ws_size,
                              hipStream_t stream) {
    const float* feats = (const float*)d_in[0];
    const float* grid  = (const float*)d_in[1];
    float* out = (float*)d_out;

    const size_t T_BYTES   = (size_t)NB * ND * NH * NW * NF * sizeof(__half); // 128 MiB
    const size_t OFF_PAYL  = T_BYTES;                                          // +16 MiB
    const size_t OFF_OUTT  = OFF_PAYL + (size_t)TOTAL * 16;                    // +32 MiB
    const size_t OFF_CNT   = OFF_OUTT + (size_t)TOTAL * NF * sizeof(float);    // +256 KiB
    const size_t NEED_FULL = OFF_CNT + (size_t)NBINS_C * HBLK * sizeof(unsigned);

    if (ws_size >= NEED_FULL) {
        char* ws = (char*)d_ws;
        __half*   T       = (__half*)ws;
        u32x4*    payload = (u32x4*)(ws + OFF_PAYL);
        float*    outT    = (float*)(ws + OFF_OUTT);
        unsigned* counts  = (unsigned*)(ws + OFF_CNT);

        const int tthreads = NB * ND * NH * NW / 4;              // 2^21
        transform_kernel<<<tthreads / 256, 256, 0, stream>>>(feats, T);

        hist_kernel<<<HBLK, 256, 0, stream>>>(grid, counts);
        scan_kernel<<<1, 128, 0, stream>>>(counts);
        scatter_kernel<<<HBLK, 256, 0, stream>>>(grid, counts, payload);
        gather_kernel<<<TOTAL / 256, 256, 0, stream>>>(T, payload, outT);
        finalize_kernel<<<TOTAL / 256, 256, 0, stream>>>(outT, out);
    } else if (ws_size >= T_BYTES) {
        __half* T = (__half*)d_ws;
        const int tthreads = NB * ND * NH * NW / 4;
        transform_kernel<<<tthreads / 256, 256, 0, stream>>>(feats, T);
        const int total = NB * HG * WG;
        trilerp_half_kernel<<<total / 256, 256, 0, stream>>>(T, grid, out);
    } else {
        const int total = NB * HG * WG;
        trilerp_f32_kernel<<<total / 256, 256, 0, stream>>>(feats, grid, out);
    }
}

// Round 4
// 463.056 us; speedup vs baseline: 1.6359x; 1.0449x over previous
//
#include <hip/hip_runtime.h>
#include <hip/hip_fp16.h>

// Trilinear grid-sample, cheap-sorted-gather pipeline (R4: parallel scan):
//  1. transform: feats [B,F,D,H,W] f32 -> T [B,D,H,W,F] fp16 (channels-last;
//     x-pair of 8 feats = 32B contiguous; 128 MiB, L3-resident).
//  2. counting sort of samples by COARSE bin = (batch, z>>2): 128 bins,
//     1 MiB z-slab per bin (fits one XCD L2). Atomic-free 3-pass partition:
//       a) hist:  per-block LDS hist -> counts[bin][blk]  (no global atomics)
//       b) scanA: 128 blocks, LDS pair-scan within each bin + bin totals
//          scanB: 1 block, exclusive scan of 128 bin totals
//          (R3's single-block serial scan was ~95us of dependent global
//           loads on one CU - the entire R3 regression.)
//       c) scatter via LDS cursors seeded with binBase+counts
//  3. gather in sorted order, XCD-range-partitioned so each z-slab is pulled
//     into one XCD's L2 once. Writes 32B result to outT[original idx]
//     (random, L2/L3-absorbed) - no inverse permutation.
//  4. finalize: fully-coalesced outT -> out[B,F,Hg,Wg] NT rewrite.

#define NB 4
#define NF 8
#define ND 128
#define NH 128
#define NW 128
#define HG 512
#define WG 512

#define PTOT (HG * WG)            // 262144 samples per batch
#define TOTAL (NB * PTOT)         // 1048576 samples
#define NBINS_C (NB * 32)         // 128 coarse bins: (batch, z>>2)
#define HBLK 512                  // hist/scatter blocks
#define SPB (TOTAL / HBLK)        // 2048 samples per hist/scatter block

typedef float        __attribute__((ext_vector_type(4))) f32x4;
typedef unsigned int __attribute__((ext_vector_type(4))) u32x4;

// ---------------- pass 1: layout transform ----------------
__global__ __launch_bounds__(256) void transform_kernel(
    const float* __restrict__ feats, __half* __restrict__ T)
{
    const size_t S = (size_t)ND * NH * NW;
    size_t tid = (size_t)blockIdx.x * blockDim.x + threadIdx.x;
    size_t b  = tid / (S / 4);
    size_t s4 = (tid - b * (S / 4)) * 4;

    const float* fb = feats + b * NF * S;
    __half* tb = T + (b * S + s4) * NF;

    f32x4 vals[NF];
#pragma unroll
    for (int f = 0; f < NF; ++f)
        vals[f] = __builtin_nontemporal_load(
            (const f32x4*)(fb + (size_t)f * S + s4));

#pragma unroll
    for (int i = 0; i < 4; ++i) {
        u32x4 hv;
#pragma unroll
        for (int f = 0; f < 4; ++f) {
            __half2 h = __floats2half2_rn(vals[2 * f][i], vals[2 * f + 1][i]);
            hv[f] = *(const unsigned*)&h;
        }
        *(u32x4*)(tb + (size_t)i * NF) = hv;   // cached: want T in L3
    }
}

// ---------------- helpers ----------------
__device__ __forceinline__ void grid_to_voxel(
    const float* __restrict__ g, float& x, float& y, float& z)
{
    x = __builtin_nontemporal_load(g + 0);
    y = __builtin_nontemporal_load(g + 1);
    z = __builtin_nontemporal_load(g + 2);
    x = fminf(fmaxf(x, -1.0f), 1.0f);
    y = fminf(fmaxf(y, -1.0f), 1.0f);
    z = fminf(fmaxf(z, -1.0f), 1.0f);
    x = (x + 1.0f) * 0.5f * (float)(NW - 1);
    y = (y + 1.0f) * 0.5f * (float)(NH - 1);
    z = (z + 1.0f) * 0.5f * (float)(ND - 1);
}

__device__ __forceinline__ int sample_bin(int idx, float z)
{
    int iz0 = min(max((int)floorf(z), 0), ND - 1);
    return ((idx >> 18) << 5) | (iz0 >> 2);       // (batch, z-slab)
}

// ---------------- sort pass a: per-block histogram (LDS only) ----------------
__global__ __launch_bounds__(256) void hist_kernel(
    const float* __restrict__ grid, unsigned* __restrict__ counts)
{
    __shared__ unsigned h[NBINS_C];
    int t = threadIdx.x, blk = blockIdx.x;
    if (t < NBINS_C) h[t] = 0u;
    __syncthreads();
#pragma unroll
    for (int k = 0; k < SPB / 256; ++k) {
        int idx = blk * SPB + k * 256 + t;
        float x, y, z;
        grid_to_voxel(grid + (size_t)idx * 3, x, y, z);
        atomicAdd(&h[sample_bin(idx, z)], 1u);
    }
    __syncthreads();
    if (t < NBINS_C) counts[(size_t)t * HBLK + blk] = h[t];
}

// ------- sort pass b1: within-bin scan over blocks (one block per bin) -----
__global__ __launch_bounds__(256) void scanA_kernel(
    unsigned* __restrict__ counts, unsigned* __restrict__ binTot)
{
    __shared__ unsigned s[256];
    int b = blockIdx.x, t = threadIdx.x;
    unsigned c0 = counts[(size_t)b * HBLK + 2 * t];
    unsigned c1 = counts[(size_t)b * HBLK + 2 * t + 1];
    s[t] = c0 + c1;
    __syncthreads();
    for (int off = 1; off < 256; off <<= 1) {
        unsigned add = (t >= off) ? s[t - off] : 0u;
        __syncthreads();
        s[t] += add;
        __syncthreads();
    }
    unsigned ex = (t == 0) ? 0u : s[t - 1];       // pairs before pair t
    counts[(size_t)b * HBLK + 2 * t]     = ex;
    counts[(size_t)b * HBLK + 2 * t + 1] = ex + c0;
    if (t == 255) binTot[b] = s[255];
}

// ------- sort pass b2: exclusive scan of bin totals (tiny, one block) ------
__global__ __launch_bounds__(128) void scanB_kernel(
    const unsigned* __restrict__ binTot, unsigned* __restrict__ binBase)
{
    __shared__ unsigned s[NBINS_C];
    int t = threadIdx.x;
    s[t] = binTot[t];
    __syncthreads();
    for (int off = 1; off < NBINS_C; off <<= 1) {
        unsigned add = (t >= off) ? s[t - off] : 0u;
        __syncthreads();
        s[t] += add;
        __syncthreads();
    }
    binBase[t] = (t == 0) ? 0u : s[t - 1];
}

// ---------------- sort pass c: scatter (LDS cursors, no global atomics) ----
__global__ __launch_bounds__(256) void scatter_kernel(
    const float* __restrict__ grid, const unsigned* __restrict__ counts,
    const unsigned* __restrict__ binBase, u32x4* __restrict__ payload)
{
    __shared__ unsigned cur[NBINS_C];
    int t = threadIdx.x, blk = blockIdx.x;
    if (t < NBINS_C)
        cur[t] = binBase[t] + counts[(size_t)t * HBLK + blk];
    __syncthreads();
#pragma unroll
    for (int k = 0; k < SPB / 256; ++k) {
        int idx = blk * SPB + k * 256 + t;
        float x, y, z;
        grid_to_voxel(grid + (size_t)idx * 3, x, y, z);
        int bin = sample_bin(idx, z);
        unsigned slot = atomicAdd(&cur[bin], 1u);
        u32x4 pl;
        pl.x = __float_as_uint(x);
        pl.y = __float_as_uint(y);
        pl.z = __float_as_uint(z);
        pl.w = (unsigned)idx;
        payload[slot] = pl;
    }
}

// ---------------- gather (sorted order, XCD-partitioned) ----------------
__device__ __forceinline__ void pair_accum(
    const u32x4& lov, const u32x4& hiv, bool hi,
    float wr, float um, float u, float acc[NF])
{
    u32x4 c0 = hi ? hiv : lov;                // x-edge clamp (ix0==127)
    const u32x4& c1 = hiv;
#pragma unroll
    for (int j = 0; j < 4; ++j) {
        unsigned u0 = c0[j], u1 = c1[j];
        float2 f0 = __half22float2(*(const __half2*)&u0);
        float2 f1 = __half22float2(*(const __half2*)&u1);
        acc[2 * j]     = fmaf(wr, fmaf(u, f1.x, um * f0.x), acc[2 * j]);
        acc[2 * j + 1] = fmaf(wr, fmaf(u, f1.y, um * f0.y), acc[2 * j + 1]);
    }
}

__global__ __launch_bounds__(256) void gather_kernel(
    const __half* __restrict__ T, const u32x4* __restrict__ payload,
    float* __restrict__ outT)
{
    // XCD range partition: blocks dispatch round-robin to the 8 XCDs, so
    // XCD x walks contiguous sorted chunks -> each z-slab enters exactly
    // one XCD's L2.
    int bid = blockIdx.x;                          // 0..4095
    int chunk = (bid & 7) * ((TOTAL / 256) / 8) + (bid >> 3);
    int slot = chunk * 256 + threadIdx.x;

    u32x4 pl = payload[slot];
    float x = __uint_as_float(pl.x);
    float y = __uint_as_float(pl.y);
    float z = __uint_as_float(pl.z);
    int b = (int)(pl.w >> 18);

    float xf = floorf(x), yf = floorf(y), zf = floorf(z);
    float u = x - xf, v = y - yf, w = z - zf;
    float um = 1.0f - u, vm = 1.0f - v, wm = 1.0f - w;

    int ix0 = min(max((int)xf, 0), NW - 1);
    int iy0 = min(max((int)yf, 0), NH - 1);
    int iy1 = min(iy0 + 1, NH - 1);
    int iz0 = min(max((int)zf, 0), ND - 1);
    int iz1 = min(iz0 + 1, ND - 1);

    int xb = min(ix0, NW - 2);
    bool hi = (ix0 != xb);

    const __half* tb = T + (size_t)b * ((size_t)ND * NH * NW) * NF;
    size_t r00 = ((size_t)(iz0 * NH + iy0) * NW + xb) * NF;
    size_t r01 = ((size_t)(iz0 * NH + iy1) * NW + xb) * NF;
    size_t r10 = ((size_t)(iz1 * NH + iy0) * NW + xb) * NF;
    size_t r11 = ((size_t)(iz1 * NH + iy1) * NW + xb) * NF;

    u32x4 L[8];
    L[0] = *(const u32x4*)(tb + r00);
    L[1] = *(const u32x4*)(tb + r00 + NF);
    L[2] = *(const u32x4*)(tb + r01);
    L[3] = *(const u32x4*)(tb + r01 + NF);
    L[4] = *(const u32x4*)(tb + r10);
    L[5] = *(const u32x4*)(tb + r10 + NF);
    L[6] = *(const u32x4*)(tb + r11);
    L[7] = *(const u32x4*)(tb + r11 + NF);

    float acc[NF];
#pragma unroll
    for (int f = 0; f < NF; ++f) acc[f] = 0.0f;

    pair_accum(L[0], L[1], hi, wm * vm, um, u, acc);
    pair_accum(L[2], L[3], hi, wm * v,  um, u, acc);
    pair_accum(L[4], L[5], hi, w  * vm, um, u, acc);
    pair_accum(L[6], L[7], hi, w  * v,  um, u, acc);

    // Write to ORIGINAL index -> finalize pass is fully coalesced.
    float* op = outT + (size_t)pl.w * NF;
    f32x4 o0, o1;
#pragma unroll
    for (int j = 0; j < 4; ++j) { o0[j] = acc[j]; o1[j] = acc[4 + j]; }
    *(f32x4*)op       = o0;
    *(f32x4*)(op + 4) = o1;
}

// ---------------- finalize: coalesced rewrite ----------------
__global__ __launch_bounds__(256) void finalize_kernel(
    const float* __restrict__ outT, float* __restrict__ out)
{
    int i = blockIdx.x * blockDim.x + threadIdx.x;
    f32x4 a = __builtin_nontemporal_load((const f32x4*)(outT + (size_t)i * NF));
    f32x4 c = __builtin_nontemporal_load((const f32x4*)(outT + (size_t)i * NF) + 1);
    int b = i >> 18;
    int p = i & (PTOT - 1);
    float* o = out + (size_t)b * NF * PTOT + p;
#pragma unroll
    for (int j = 0; j < 4; ++j) {
        __builtin_nontemporal_store(a[j], o + (size_t)j * PTOT);
        __builtin_nontemporal_store(c[j], o + (size_t)(4 + j) * PTOT);
    }
}

// ---------------- fallbacks ----------------
__global__ __launch_bounds__(256) void trilerp_half_kernel(
    const __half* __restrict__ T,
    const float* __restrict__ grid,
    float* __restrict__ out)
{
    const int P = HG * WG;
    int idx = blockIdx.x * blockDim.x + threadIdx.x;
    int b = idx >> 18;
    int p = idx & (P - 1);

    float x, y, z;
    grid_to_voxel(grid + (size_t)idx * 3, x, y, z);

    float xf = floorf(x), yf = floorf(y), zf = floorf(z);
    float u = x - xf, v = y - yf, w = z - zf;
    float um = 1.0f - u, vm = 1.0f - v, wm = 1.0f - w;

    int ix0 = min(max((int)xf, 0), NW - 1);
    int iy0 = min(max((int)yf, 0), NH - 1);
    int iy1 = min(iy0 + 1, NH - 1);
    int iz0 = min(max((int)zf, 0), ND - 1);
    int iz1 = min(iz0 + 1, ND - 1);

    int xb = min(ix0, NW - 2);
    bool hi = (ix0 != xb);

    const __half* tb = T + (size_t)b * ((size_t)ND * NH * NW) * NF;
    size_t r00 = ((size_t)(iz0 * NH + iy0) * NW + xb) * NF;
    size_t r01 = ((size_t)(iz0 * NH + iy1) * NW + xb) * NF;
    size_t r10 = ((size_t)(iz1 * NH + iy0) * NW + xb) * NF;
    size_t r11 = ((size_t)(iz1 * NH + iy1) * NW + xb) * NF;

    u32x4 L[8];
    L[0] = *(const u32x4*)(tb + r00);
    L[1] = *(const u32x4*)(tb + r00 + NF);
    L[2] = *(const u32x4*)(tb + r01);
    L[3] = *(const u32x4*)(tb + r01 + NF);
    L[4] = *(const u32x4*)(tb + r10);
    L[5] = *(const u32x4*)(tb + r10 + NF);
    L[6] = *(const u32x4*)(tb + r11);
    L[7] = *(const u32x4*)(tb + r11 + NF);

    float acc[NF];
#pragma unroll
    for (int f = 0; f < NF; ++f) acc[f] = 0.0f;

    pair_accum(L[0], L[1], hi, wm * vm, um, u, acc);
    pair_accum(L[2], L[3], hi, wm * v,  um, u, acc);
    pair_accum(L[4], L[5], hi, w  * vm, um, u, acc);
    pair_accum(L[6], L[7], hi, w  * v,  um, u, acc);

    float* o = out + (size_t)b * NF * P + p;
#pragma unroll
    for (int f = 0; f < NF; ++f)
        __builtin_nontemporal_store(acc[f], o + (size_t)f * P);
}

__global__ __launch_bounds__(256) void trilerp_f32_kernel(
    const float* __restrict__ feats,
    const float* __restrict__ grid,
    float* __restrict__ out)
{
    const int P = HG * WG;
    int idx = blockIdx.x * blockDim.x + threadIdx.x;
    int b = idx >> 18;
    int p = idx & (P - 1);

    const float* g = grid + (size_t)idx * 3;
    float x = g[0], y = g[1], z = g[2];
    x = fminf(fmaxf(x, -1.0f), 1.0f);
    y = fminf(fmaxf(y, -1.0f), 1.0f);
    z = fminf(fmaxf(z, -1.0f), 1.0f);
    x = (x + 1.0f) * 0.5f * (float)(NW - 1);
    y = (y + 1.0f) * 0.5f * (float)(NH - 1);
    z = (z + 1.0f) * 0.5f * (float)(ND - 1);

    float xf = floorf(x), yf = floorf(y), zf = floorf(z);
    float u = x - xf, v = y - yf, w = z - zf;

    int ix0 = min(max((int)xf, 0), NW - 1);
    int ix1 = min(ix0 + 1, NW - 1);
    int iy0 = min(max((int)yf, 0), NH - 1);
    int iy1 = min(iy0 + 1, NH - 1);
    int iz0 = min(max((int)zf, 0), ND - 1);
    int iz1 = min(iz0 + 1, ND - 1);

    float um = 1.0f - u, vm = 1.0f - v, wm = 1.0f - w;
    float w000 = um * vm * wm, w100 = u * vm * wm;
    float w010 = um * v * wm,  w110 = u * v * wm;
    float w001 = um * vm * w,  w101 = u * vm * w;
    float w011 = um * v * w,   w111 = u * v * w;

    int off00 = (iz0 * NH + iy0) * NW;
    int off01 = (iz0 * NH + iy1) * NW;
    int off10 = (iz1 * NH + iy0) * NW;
    int off11 = (iz1 * NH + iy1) * NW;

    const size_t fstride = (size_t)ND * NH * NW;
    const float* fb = feats + (size_t)b * NF * fstride;
    float* o = out + (size_t)b * NF * P + p;

#pragma unroll
    for (int f = 0; f < NF; ++f) {
        const float* fp = fb + (size_t)f * fstride;
        float r = w000 * fp[off00 + ix0] + w100 * fp[off00 + ix1]
                + w010 * fp[off01 + ix0] + w110 * fp[off01 + ix1]
                + w001 * fp[off10 + ix0] + w101 * fp[off10 + ix1]
                + w011 * fp[off11 + ix0] + w111 * fp[off11 + ix1];
        o[(size_t)f * P] = r;
    }
}

extern "C" void kernel_launch(void* const* d_in, const int* in_sizes, int n_in,
                              void* d_out, int out_size, void* d_ws, size_t ws_size,
                              hipStream_t stream) {
    const float* feats = (const float*)d_in[0];
    const float* grid  = (const float*)d_in[1];
    float* out = (float*)d_out;

    const size_t T_BYTES   = (size_t)NB * ND * NH * NW * NF * sizeof(__half); // 128 MiB
    const size_t OFF_PAYL  = T_BYTES;                                          // +16 MiB
    const size_t OFF_OUTT  = OFF_PAYL + (size_t)TOTAL * 16;                    // +32 MiB
    const size_t OFF_CNT   = OFF_OUTT + (size_t)TOTAL * NF * sizeof(float);    // +256 KiB
    const size_t OFF_BTOT  = OFF_CNT + (size_t)NBINS_C * HBLK * sizeof(unsigned);
    const size_t OFF_BBASE = OFF_BTOT + (size_t)NBINS_C * sizeof(unsigned);
    const size_t NEED_FULL = OFF_BBASE + (size_t)NBINS_C * sizeof(unsigned);

    if (ws_size >= NEED_FULL) {
        char* ws = (char*)d_ws;
        __half*   T       = (__half*)ws;
        u32x4*    payload = (u32x4*)(ws + OFF_PAYL);
        float*    outT    = (float*)(ws + OFF_OUTT);
        unsigned* counts  = (unsigned*)(ws + OFF_CNT);
        unsigned* binTot  = (unsigned*)(ws + OFF_BTOT);
        unsigned* binBase = (unsigned*)(ws + OFF_BBASE);

        const int tthreads = NB * ND * NH * NW / 4;              // 2^21
        transform_kernel<<<tthreads / 256, 256, 0, stream>>>(feats, T);

        hist_kernel<<<HBLK, 256, 0, stream>>>(grid, counts);
        scanA_kernel<<<NBINS_C, 256, 0, stream>>>(counts, binTot);
        scanB_kernel<<<1, NBINS_C, 0, stream>>>(binTot, binBase);
        scatter_kernel<<<HBLK, 256, 0, stream>>>(grid, counts, binBase, payload);
        gather_kernel<<<TOTAL / 256, 256, 0, stream>>>(T, payload, outT);
        finalize_kernel<<<TOTAL / 256, 256, 0, stream>>>(outT, out);
    } else if (ws_size >= T_BYTES) {
        __half* T = (__half*)d_ws;
        const int tthreads = NB * ND * NH * NW / 4;
        transform_kernel<<<tthreads / 256, 256, 0, stream>>>(feats, T);
        const int total = NB * HG * WG;
        trilerp_half_kernel<<<total / 256, 256, 0, stream>>>(T, grid, out);
    } else {
        const int total = NB * HG * WG;
        trilerp_f32_kernel<<<total / 256, 256, 0, stream>>>(feats, grid, out);
    }
}